// Round 15
// baseline (36000.595 us; speedup 1.0000x reference)
//
#include <hip/hip_runtime.h>
#include <hip/hip_bf16.h>

// LSTMModel_with_theta: B=64, T=2048, H=256, 2-layer LSTM -> mean_t -> MLP.
//
// Round 15: multi-chain interleave (r8 principle, r10 protocol, r8 confounds fixed).
//  - r4/r10 both ~3us/step across different sync semantics => MALL store->load
//    visibility V + serial reload RTT dominates. r11-14 attacked mechanics and
//    scope; all failed. This round hides V behind TIME: each WG processes all
//    4 independent batch-group chains round-robin (weights shared across batch,
//    same registers!); a chain's peer data is published 4 sub-steps (~1.5us)
//    before consumption -> steady-state first-check pass if V <= 1.5us.
//  - 6 WGs: 2x L0 (unit-half x 4 groups), 4x L1 (unit-quarter x 4 groups).
//  - Everything else r10 verbatim: tagged u32 (t+1)<<16|bf16, relaxed agent
//    atomics, coop staging, coalesced publishes, gbuf EW, lgkmcnt-only bars,
//    static reg indices (chain loop unrolled).

#define BB 64
#define TT 2048
#define HH 256
#define D0 16
#define D1 4

typedef short s16x8 __attribute__((ext_vector_type(8)));
typedef float f32x4 __attribute__((ext_vector_type(4)));

__device__ inline unsigned short f2bf(float f) {
  unsigned u = __float_as_uint(f);
  u += 0x7fff + ((u >> 16) & 1);          // RNE
  return (unsigned short)(u >> 16);
}
__device__ inline float sigm(float x) { return 1.f / (1.f + __expf(-x)); }
__device__ inline float tanh_f(float x) { return 1.f - 2.f / (__expf(2.f * x) + 1.f); }

__device__ inline unsigned long long ld64(const unsigned int* p) {
  return __hip_atomic_load((const unsigned long long*)p, __ATOMIC_RELAXED,
                           __HIP_MEMORY_SCOPE_AGENT);
}
__device__ inline void st32(unsigned int* p, unsigned int v) {
  __hip_atomic_store(p, v, __ATOMIC_RELAXED, __HIP_MEMORY_SCOPE_AGENT);
}
__device__ inline void st32i(int* p, int v) {
  __hip_atomic_store(p, v, __ATOMIC_RELAXED, __HIP_MEMORY_SCOPE_AGENT);
}
__device__ inline int ld32i(const int* p) {
  return __hip_atomic_load(p, __ATOMIC_RELAXED, __HIP_MEMORY_SCOPE_AGENT);
}
__device__ inline void wg_bar() {
  asm volatile("s_waitcnt lgkmcnt(0)" ::: "memory");
  __builtin_amdgcn_sched_barrier(0);
  __builtin_amdgcn_s_barrier();
  __builtin_amdgcn_sched_barrier(0);
}
__device__ inline bool tag2ok(unsigned long long q, unsigned int tg) {
  return (((q >> 16) & 0xFFFFu) == tg) & ((unsigned)(q >> 48) == tg);
}

#define MFMA(a, b, c) __builtin_amdgcn_mfma_f32_16x16x32_bf16((a), (b), (c), 0, 0, 0)

__global__ void xt_kernel(const float* __restrict__ x, float* __restrict__ xT) {
  int i = blockIdx.x * 256 + threadIdx.x;   // 131072 total
  int b = i & 63, t = i >> 6;
  xT[(size_t)t * BB + b] = x[(size_t)b * TT + t];
}

__global__ __launch_bounds__(512, 1)
void lstm_kernel(const float* __restrict__ Wx0, const float* __restrict__ Wh0,
                 const float* __restrict__ b0v,
                 const float* __restrict__ Wx1, const float* __restrict__ Wh1,
                 const float* __restrict__ b1v,
                 const float* __restrict__ xT,
                 unsigned int* __restrict__ seqring,   // [4][D0][16][256] tagged u32
                 unsigned int* __restrict__ h1ring,    // [4][D1][16][256] tagged u32
                 float* __restrict__ hmean, int* prog)
{
  __shared__ __align__(16) char AbAll[4 * 8192];   // L0: per-chain h tile; L1: Ab|Ab1
  __shared__ float gbuf[16][4][66];                // L1 gate gather

  const int bid  = blockIdx.x;
  const int tid  = threadIdx.x;
  const int lane = tid & 63;
  const int w    = tid >> 6;      // wave 0..7
  const int u16  = lane & 15;
  const int kgrp = lane >> 4;
  const int arow = lane & 15;

  if (bid < 2) {
    // ========== LAYER 0: WG = unit-half ho, ALL 4 chains ==========
    const int ho = bid, po = 1 - ho;
    const int U = ho * 128 + w * 16 + u16;       // lane's unit (all 4 gates)
    s16x8 bw[32];                                // phase layout, static reg indices
#pragma unroll
    for (int n = 0; n < 4; ++n)
#pragma unroll
      for (int ph = 0; ph < 2; ++ph)
#pragma unroll
        for (int i = 0; i < 4; ++i) {
          const int ks = (ph == 0 ? ho : po) * 4 + i;   // runtime, address-only
          const int col = n * 256 + U;
#pragma unroll
          for (int j = 0; j < 8; ++j)
            bw[n * 8 + ph * 4 + i][j] =
                (short)f2bf(Wh0[(size_t)(ks * 32 + kgrp * 8 + j) * 1024 + col]);
        }
    float bE[4], xE[4];
#pragma unroll
    for (int n = 0; n < 4; ++n) { bE[n] = b0v[n * 256 + U]; xE[n] = Wx0[n * 256 + U]; }

    const int srow = tid >> 5, spc = (tid & 31) * 4;    // partner stage: 4 u32/thread
    float cL[4][4] = {{0,0,0,0},{0,0,0,0},{0,0,0,0},{0,0,0,0}};
    unsigned long long pq[4][2];                        // per-chain prefetched partner

    for (int t = 0; t < TT; ++t) {
#pragma unroll
      for (int c = 0; c < 4; ++c) {
        unsigned int* sr = seqring + (size_t)c * D0 * 4096;
        char* Abc = AbAll + c * 8192;
        if ((t & 7) == 0 && t >= 16 && tid < 4)         // L1 back-pressure (coarse)
          while (ld32i(&prog[(c * 4 + tid) * 16]) < t - 8) __builtin_amdgcn_s_sleep(8);
        wg_bar();   // top of sub-step

        const unsigned int* sb = sr + ((t - 1) & (D0 - 1)) * 4096 + srow * 256 + po * 128 + spc;
        float xr[4];
#pragma unroll
        for (int r = 0; r < 4; ++r) xr[r] = xT[(size_t)t * BB + c * 16 + kgrp * 4 + r];

        f32x4 acc[4] = {{0,0,0,0},{0,0,0,0},{0,0,0,0},{0,0,0,0}};
        if (t > 0) {
          // own-half MFMAs from LDS (overlap the tag check)
          s16x8 ao[4];
#pragma unroll
          for (int i = 0; i < 4; ++i) {
            const int ks = ho * 4 + i;
            ao[i] = *(const s16x8*)(Abc + ((arow * 512 + (ks * 32 + kgrp * 8) * 2) ^ ((arow & 7) << 4)));
          }
#pragma unroll
          for (int i = 0; i < 4; ++i)
#pragma unroll
            for (int n = 0; n < 4; ++n) acc[n] = MFMA(ao[i], bw[n * 8 + i], acc[n]);
          // check prefetched partner h(c, t-1) (published 4 sub-steps ago)
          const unsigned int tg = (unsigned int)t;
          unsigned long long q0 = pq[c][0], q1 = pq[c][1];
          for (;;) {
            if (__all(tag2ok(q0, tg) & tag2ok(q1, tg))) break;
            __builtin_amdgcn_s_sleep(1);
            q0 = ld64(sb); q1 = ld64(sb + 2);
          }
          const unsigned int lo = (unsigned)(q0 & 0xFFFF) | (((unsigned)(q0 >> 32) & 0xFFFF) << 16);
          const unsigned int hi = (unsigned)(q1 & 0xFFFF) | (((unsigned)(q1 >> 32) & 0xFFFF) << 16);
          *(uint2*)(Abc + ((srow * 512 + (po * 128 + spc) * 2) ^ ((srow & 7) << 4))) = (uint2){lo, hi};
        }
        wg_bar();   // partner staged
        if (t > 0) {
          s16x8 ap[4];
#pragma unroll
          for (int i = 0; i < 4; ++i) {
            const int ks = po * 4 + i;
            ap[i] = *(const s16x8*)(Abc + ((arow * 512 + (ks * 32 + kgrp * 8) * 2) ^ ((arow & 7) << 4)));
          }
#pragma unroll
          for (int i = 0; i < 4; ++i)
#pragma unroll
            for (int n = 0; n < 4; ++n) acc[n] = MFMA(ap[i], bw[n * 8 + 4 + i], acc[n]);
        }
        // EW per-lane; publish tagged + own-half h into LDS
        const unsigned int tagw = (unsigned)(t + 1) << 16;
#pragma unroll
        for (int r = 0; r < 4; ++r) {
          const int row = kgrp * 4 + r;
          const float gi = acc[0][r] + bE[0] + xr[r] * xE[0];
          const float gf = acc[1][r] + bE[1] + xr[r] * xE[1];
          const float gg = acc[2][r] + bE[2] + xr[r] * xE[2];
          const float go = acc[3][r] + bE[3] + xr[r] * xE[3];
          cL[c][r] = sigm(gf) * cL[c][r] + sigm(gi) * tanh_f(gg);
          const float hv = sigm(go) * tanh_f(cL[c][r]);
          const unsigned short hb = f2bf(hv);
          st32(sr + (t & (D0 - 1)) * 4096 + row * 256 + U, tagw | hb);
          *(unsigned short*)(Abc + ((row * 512 + U * 2) ^ ((row & 7) << 4))) = hb;
        }
        // prefetch partner h(c, t): checked 4 sub-steps from now
        {
          const unsigned int* pb = sr + (t & (D0 - 1)) * 4096 + srow * 256 + po * 128 + spc;
          pq[c][0] = ld64(pb); pq[c][1] = ld64(pb + 2);
        }
      }
    }
  } else if (bid < 6) {
    // ========== LAYER 1: WG = 64-unit quarter q, ALL 4 chains ==========
    const int q = bid - 2;
    const int gp = w >> 2;            // gate pair
    const int uo = (w & 3) * 16;      // unit offset in WG's 64
    const int ub = q * 64;
    s16x8 bw[2][16];                  // static idx only
#pragma unroll
    for (int nt = 0; nt < 2; ++nt)
#pragma unroll
      for (int ks = 0; ks < 16; ++ks) {
        const int col = (2 * gp + nt) * 256 + ub + uo + u16;
#pragma unroll
        for (int j = 0; j < 8; ++j) {
          const int k = (ks & 7) * 32 + kgrp * 8 + j;
          bw[nt][ks][j] = (short)f2bf((ks < 8) ? Wx1[(size_t)k * 1024 + col]
                                               : Wh1[(size_t)k * 1024 + col]);
        }
      }
    const int eur = tid >> 5, eu2 = (tid & 31) * 2;
    float bE[4][2];
#pragma unroll
    for (int ga = 0; ga < 4; ++ga)
#pragma unroll
      for (int uu = 0; uu < 2; ++uu)
        bE[ga][uu] = b1v[ga * 256 + ub + eu2 + uu];

    char* Ab  = AbAll;                // h0 stage (reused across chains)
    char* Ab1 = AbAll + 8192;         // h1 stage
    const int srow = tid >> 5, sc8 = (tid & 31) * 8;    // stage: 8 u32/thread
    float cL[4][2] = {{0,0},{0,0},{0,0},{0,0}};
    float hs[4][2] = {{0,0},{0,0},{0,0},{0,0}};
    unsigned long long qh0[4][4], qh1[4][4];

    // prologue: prefetch h0(c, 0)
#pragma unroll
    for (int c = 0; c < 4; ++c) {
      const unsigned int* sb = seqring + (size_t)c * D0 * 4096 + srow * 256 + sc8;
#pragma unroll
      for (int i = 0; i < 4; ++i) qh0[c][i] = ld64(sb + i * 2);
    }

    for (int t = 0; t < TT; ++t) {
#pragma unroll
      for (int c = 0; c < 4; ++c) {
        unsigned int* sr = seqring + (size_t)c * D0 * 4096;
        unsigned int* hr = h1ring  + (size_t)c * D1 * 4096;
        if ((t & 3) == 3 && tid == 0) st32i(&prog[(c * 4 + q) * 16], t);
        // ---- h0(c, t): check prefetched (L0 runs ahead) ----
        {
          const unsigned int* sb = sr + (t & (D0 - 1)) * 4096 + srow * 256 + sc8;
          const unsigned int tg = (unsigned int)(t + 1);
          for (;;) {
            bool ok = true;
#pragma unroll
            for (int i = 0; i < 4; ++i) ok &= tag2ok(qh0[c][i], tg);
            if (__all(ok)) break;
            __builtin_amdgcn_s_sleep(1);
#pragma unroll
            for (int i = 0; i < 4; ++i) qh0[c][i] = ld64(sb + i * 2);
          }
          unsigned int wv[4];
#pragma unroll
          for (int i = 0; i < 4; ++i)
            wv[i] = (unsigned)(qh0[c][i] & 0xFFFF) | (((unsigned)(qh0[c][i] >> 32) & 0xFFFF) << 16);
          *(uint4*)(Ab + ((srow * 512 + sc8 * 2) ^ ((srow & 7) << 4))) =
              (uint4){wv[0], wv[1], wv[2], wv[3]};
        }
        wg_bar();   // h0 staged
        f32x4 acc0 = {0,0,0,0}, acc1 = {0,0,0,0};
        {
          s16x8 a[8];
#pragma unroll
          for (int ks = 0; ks < 8; ++ks)
            a[ks] = *(const s16x8*)(Ab + ((arow * 512 + (ks * 32 + kgrp * 8) * 2) ^ ((arow & 7) << 4)));
#pragma unroll
          for (int ks = 0; ks < 8; ++ks) {
            acc0 = MFMA(a[ks], bw[0][ks], acc0);
            acc1 = MFMA(a[ks], bw[1][ks], acc1);
          }
        }
        // ---- h1(c, t-1): check prefetched (published 4 sub-steps ago) ----
        if (t > 0) {
          const unsigned int* sbh1 = hr + ((t - 1) & (D1 - 1)) * 4096 + srow * 256 + sc8;
          const unsigned int tg = (unsigned int)t;
          for (;;) {
            bool ok = true;
#pragma unroll
            for (int i = 0; i < 4; ++i) ok &= tag2ok(qh1[c][i], tg);
            if (__all(ok)) break;
            __builtin_amdgcn_s_sleep(1);
#pragma unroll
            for (int i = 0; i < 4; ++i) qh1[c][i] = ld64(sbh1 + i * 2);
          }
          unsigned int wv[4];
#pragma unroll
          for (int i = 0; i < 4; ++i)
            wv[i] = (unsigned)(qh1[c][i] & 0xFFFF) | (((unsigned)(qh1[c][i] >> 32) & 0xFFFF) << 16);
          *(uint4*)(Ab1 + ((srow * 512 + sc8 * 2) ^ ((srow & 7) << 4))) =
              (uint4){wv[0], wv[1], wv[2], wv[3]};
        }
        wg_bar();   // h1 staged
        if (t > 0) {
          s16x8 a[8];
#pragma unroll
          for (int kk = 0; kk < 8; ++kk)
            a[kk] = *(const s16x8*)(Ab1 + ((arow * 512 + (kk * 32 + kgrp * 8) * 2) ^ ((arow & 7) << 4)));
#pragma unroll
          for (int kk = 0; kk < 8; ++kk) {
            acc0 = MFMA(a[kk], bw[0][8 + kk], acc0);
            acc1 = MFMA(a[kk], bw[1][8 + kk], acc1);
          }
        }
#pragma unroll
        for (int r = 0; r < 4; ++r) {
          gbuf[kgrp * 4 + r][2 * gp + 0][uo + u16] = acc0[r];
          gbuf[kgrp * 4 + r][2 * gp + 1][uo + u16] = acc1[r];
        }
        wg_bar();   // gates gathered

        unsigned short hb[2];
#pragma unroll
        for (int uu = 0; uu < 2; ++uu) {
          const int u = eu2 + uu;
          const float gi = gbuf[eur][0][u] + bE[0][uu];
          const float gf = gbuf[eur][1][u] + bE[1][uu];
          const float gg = gbuf[eur][2][u] + bE[2][uu];
          const float go = gbuf[eur][3][u] + bE[3][uu];
          cL[c][uu] = sigm(gf) * cL[c][uu] + sigm(gi) * tanh_f(gg);
          const float hv = sigm(go) * tanh_f(cL[c][uu]);
          hs[c][uu] += hv;
          hb[uu] = f2bf(hv);
        }
        const unsigned int tagw = (unsigned)(t + 1) << 16;
        st32(hr + (t & (D1 - 1)) * 4096 + eur * 256 + ub + eu2,     tagw | hb[0]);
        st32(hr + (t & (D1 - 1)) * 4096 + eur * 256 + ub + eu2 + 1, tagw | hb[1]);
        // ---- prefetch for (c, t+1): in flight for the next 4 sub-steps ----
        {
          const unsigned int* sb = sr + ((t + 1) & (D0 - 1)) * 4096 + srow * 256 + sc8;
#pragma unroll
          for (int i = 0; i < 4; ++i) qh0[c][i] = ld64(sb + i * 2);
          const unsigned int* hb2 = hr + (t & (D1 - 1)) * 4096 + srow * 256 + sc8;
#pragma unroll
          for (int i = 0; i < 4; ++i) qh1[c][i] = ld64(hb2 + i * 2);
        }
      }
    }
#pragma unroll
    for (int c = 0; c < 4; ++c)
#pragma unroll
      for (int uu = 0; uu < 2; ++uu)
        hmean[(size_t)(c * 16 + eur) * HH + ub + eu2 + uu] = hs[c][uu] * (1.f / TT);
  }
}

__global__ __launch_bounds__(256)
void mlp_kernel(const float* __restrict__ theta, const float* __restrict__ Wtp,
                const float* __restrict__ btp, const float* __restrict__ Wl1,
                const float* __restrict__ bl1, const float* __restrict__ Wl2,
                const float* __restrict__ bl2, const float* __restrict__ Wo,
                const float* __restrict__ bo, const float* __restrict__ hmean,
                float* __restrict__ out)
{
  const int b = blockIdx.x;
  const int j = threadIdx.x;
  __shared__ float z[2 * HH];
  __shared__ float z1s[HH];
  __shared__ float red[256];

  float tp = btp[j];
#pragma unroll
  for (int d = 0; d < 5; ++d) tp += theta[b * 5 + d] * Wtp[d * HH + j];
  z[j] = hmean[(size_t)b * HH + j];
  z[HH + j] = tp;
  __syncthreads();

  float a1 = bl1[j];
  for (int k = 0; k < 2 * HH; ++k) a1 += z[k] * Wl1[(size_t)k * 256 + j];
  a1 = (a1 > 0.f) ? a1 : (__expf(a1) - 1.f);
  z1s[j] = a1;
  __syncthreads();

  float a2 = bl2[j];
  for (int k = 0; k < HH; ++k) a2 += z1s[k] * Wl2[(size_t)k * 256 + j];
  a2 = (a2 > 0.f) ? a2 : (__expf(a2) - 1.f);
  red[j] = a2 * Wo[j];
  __syncthreads();
  for (int s = 128; s > 0; s >>= 1) {
    if (j < s) red[j] += red[j + s];
    __syncthreads();
  }
  if (j == 0) out[b] = red[0] + bo[0];
}

extern "C" void kernel_launch(void* const* d_in, const int* in_sizes, int n_in,
                              void* d_out, int out_size, void* d_ws, size_t ws_size,
                              hipStream_t stream) {
  const float* x    = (const float*)d_in[0];
  const float* theta= (const float*)d_in[1];
  const float* Wx0  = (const float*)d_in[2];
  const float* Wh0  = (const float*)d_in[3];
  const float* b0   = (const float*)d_in[4];
  const float* Wx1  = (const float*)d_in[5];
  const float* Wh1  = (const float*)d_in[6];
  const float* b1   = (const float*)d_in[7];
  const float* Wtp  = (const float*)d_in[8];
  const float* btp  = (const float*)d_in[9];
  const float* Wl1  = (const float*)d_in[10];
  const float* bl1  = (const float*)d_in[11];
  const float* Wl2  = (const float*)d_in[12];
  const float* bl2  = (const float*)d_in[13];
  const float* Wo   = (const float*)d_in[14];
  const float* bo   = (const float*)d_in[15];

  // ws: prog 8KB | seqring [4][16][16][256] u32 1MB | h1ring [4][4][16][256] u32 256KB
  //     | hmean 64KB | xT 512KB.  prog+rings memset each launch (tag 0 never valid).
  char* ws = (char*)d_ws;
  int* prog             = (int*)ws;
  unsigned int* seqring = (unsigned int*)(ws + 8192);
  unsigned int* h1ring  = (unsigned int*)(ws + 8192 + 1048576);
  float* hmean          = (float*)(ws + 8192 + 1048576 + 262144);
  float* xT             = (float*)(ws + 8192 + 1048576 + 262144 + 65536);
  const size_t WS_NEED = 8192ull + 1048576 + 262144 + 65536 + 524288;
  if (ws_size < WS_NEED) return;

  hipMemsetAsync(d_ws, 0, 8192 + 1048576 + 262144, stream);

  xt_kernel<<<dim3((BB * TT) / 256), dim3(256), 0, stream>>>(x, xT);
  lstm_kernel<<<dim3(6), dim3(512), 0, stream>>>(
      Wx0, Wh0, b0, Wx1, Wh1, b1, xT, seqring, h1ring, hmean, prog);
  mlp_kernel<<<dim3(BB), dim3(256), 0, stream>>>(
      theta, Wtp, btp, Wl1, bl1, Wl2, bl2, Wo, bo, hmean, (float*)d_out);
}

// Round 16
// 6277.742 us; speedup vs baseline: 5.7346x; 5.7346x over previous
//
#include <hip/hip_runtime.h>
#include <hip/hip_bf16.h>

// LSTMModel_with_theta: B=64, T=2048, H=256, 2-layer LSTM -> mean_t -> MLP.
//
// Round 16: r10 core + h0 path rebuilt so L1 never waits on it.
//  - Insight (r15): loads sample at ISSUE time. Prefetch validity requires
//    producer published BEFORE issue. h1 (true recurrence) can't satisfy
//    that; h0 CAN - L0 runs ahead (back-pressure deleted, append-only h0).
//  - h0: L0 publishes packed bf16-pairs to full-T seq0 (64MB ws) via relaxed
//    agent stores, then vmcnt+lgkm drain + barrier + per-WG flag (drain on
//    L0 = off critical path). L1 reads h0 with PLAIN CACHED uint4 loads,
//    prefetched 1 step early, guarded by lazily-refreshed flag (seen>=t+2
//    at issue => published before issue => valid). Steady-state h0 cost ~0.
//  - h1 + L0-partner exchanges: r10 tagged protocol verbatim (D0=4, D1=2 -
//    both safe by mutual-progress; tags disambiguate reuse).
//  - xT dropped: L0 reads x directly (64B line covers 16 steps -> L1-hit).

#define BB 64
#define TT 2048
#define HH 256
#define D0 4
#define D1 2

typedef short s16x8 __attribute__((ext_vector_type(8)));
typedef float f32x4 __attribute__((ext_vector_type(4)));

__device__ inline unsigned short f2bf(float f) {
  unsigned u = __float_as_uint(f);
  u += 0x7fff + ((u >> 16) & 1);          // RNE
  return (unsigned short)(u >> 16);
}
__device__ inline float sigm(float x) { return 1.f / (1.f + __expf(-x)); }
__device__ inline float tanh_f(float x) { return 1.f - 2.f / (__expf(2.f * x) + 1.f); }

__device__ inline unsigned long long ld64(const unsigned int* p) {
  return __hip_atomic_load((const unsigned long long*)p, __ATOMIC_RELAXED,
                           __HIP_MEMORY_SCOPE_AGENT);
}
__device__ inline void st32(unsigned int* p, unsigned int v) {
  __hip_atomic_store(p, v, __ATOMIC_RELAXED, __HIP_MEMORY_SCOPE_AGENT);
}
__device__ inline void st32i(int* p, int v) {
  __hip_atomic_store(p, v, __ATOMIC_RELAXED, __HIP_MEMORY_SCOPE_AGENT);
}
__device__ inline int ld32i(const int* p) {
  return __hip_atomic_load(p, __ATOMIC_RELAXED, __HIP_MEMORY_SCOPE_AGENT);
}
// barrier, LDS-fence only (tagged global stores fly free)
__device__ inline void wg_bar() {
  asm volatile("s_waitcnt lgkmcnt(0)" ::: "memory");
  __builtin_amdgcn_sched_barrier(0);
  __builtin_amdgcn_s_barrier();
  __builtin_amdgcn_sched_barrier(0);
}
// producer-side full drain (global stores acked at coherence point + LDS)
__device__ inline void drain_bar() {
  asm volatile("s_waitcnt vmcnt(0) lgkmcnt(0)" ::: "memory");
  __builtin_amdgcn_sched_barrier(0);
  __builtin_amdgcn_s_barrier();
  __builtin_amdgcn_sched_barrier(0);
}
__device__ inline bool tag2ok(unsigned long long q, unsigned int tg) {
  return (((q >> 16) & 0xFFFFu) == tg) & ((unsigned)(q >> 48) == tg);
}

#define MFMA(a, b, c) __builtin_amdgcn_mfma_f32_16x16x32_bf16((a), (b), (c), 0, 0, 0)

__global__ __launch_bounds__(512, 1)
void lstm_kernel(const float* __restrict__ Wx0, const float* __restrict__ Wh0,
                 const float* __restrict__ b0v,
                 const float* __restrict__ Wx1, const float* __restrict__ Wh1,
                 const float* __restrict__ b1v,
                 const float* __restrict__ x,
                 unsigned int* __restrict__ seqring,   // [4][D0][16][256] tagged u32 (L0<->L0)
                 unsigned int* __restrict__ h1ring,    // [4][D1][16][256] tagged u32 (L1 peers)
                 unsigned int* __restrict__ seq0p,     // [T][64][128] packed bf16-pair u32
                 float* __restrict__ hmean, int* flags)
{
  __shared__ __align__(16) char Ab [8192];       // [16 rows][256 units] bf16, swizzled
  __shared__ __align__(16) char Ab1[8192];       // L1: h1(t-1)
  __shared__ float gbuf[16][4][66];              // L1 gate gather
  __shared__ int smem_seen;

  const int bid  = blockIdx.x;
  const int tid  = threadIdx.x;
  const int lane = tid & 63;
  const int w    = tid >> 6;      // wave 0..7
  const int u16  = lane & 15;
  const int kgrp = lane >> 4;
  const int arow = lane & 15;

  int* f0 = flags + 512;          // L0 publish flags: [(g*2+ho)*16]

  if (bid < 8) {
    // ========== LAYER 0: 2 WGs/group x 128 units, K=256 ==========
    const int g = bid >> 1, ho = bid & 1, po = 1 - ho;
    const int U = ho * 128 + w * 16 + u16;       // lane's unit (all 4 gates)
    s16x8 bw[32];                                // phase layout, static reg indices
#pragma unroll
    for (int n = 0; n < 4; ++n)
#pragma unroll
      for (int ph = 0; ph < 2; ++ph)
#pragma unroll
        for (int i = 0; i < 4; ++i) {
          const int ks = (ph == 0 ? ho : po) * 4 + i;   // runtime, address-only
          const int col = n * 256 + U;
#pragma unroll
          for (int j = 0; j < 8; ++j)
            bw[n * 8 + ph * 4 + i][j] =
                (short)f2bf(Wh0[(size_t)(ks * 32 + kgrp * 8 + j) * 1024 + col]);
        }
    float bE[4], xE[4];
#pragma unroll
    for (int n = 0; n < 4; ++n) { bE[n] = b0v[n * 256 + U]; xE[n] = Wx0[n * 256 + U]; }

    unsigned int* sr = seqring + (size_t)g * D0 * 4096;
    int* myflag = &f0[(g * 2 + ho) * 16];
    const int srow = tid >> 5, spc = (tid & 31) * 4;    // partner stage: 4 u32/thread
    float cL[4] = {0.f, 0.f, 0.f, 0.f};
    unsigned long long pq0 = 0, pq1 = 0;                // prefetched partner h

    for (int t = 0; t < TT; ++t) {
      // x loads early (64B line covers 16 t's -> L1-hit most steps)
      float xr[4];
#pragma unroll
      for (int r = 0; r < 4; ++r) xr[r] = x[(size_t)(g * 16 + kgrp * 4 + r) * TT + t];

      const unsigned int* sb = sr + ((t - 1) & (D0 - 1)) * 4096 + srow * 256 + po * 128 + spc;
      f32x4 acc[4] = {{0,0,0,0},{0,0,0,0},{0,0,0,0},{0,0,0,0}};
      if (t > 0) {
        // own-half MFMAs from LDS (cover partner visibility window)
        s16x8 ao[4];
#pragma unroll
        for (int i = 0; i < 4; ++i) {
          const int ks = ho * 4 + i;
          ao[i] = *(const s16x8*)(Ab + ((arow * 512 + (ks * 32 + kgrp * 8) * 2) ^ ((arow & 7) << 4)));
        }
#pragma unroll
        for (int i = 0; i < 4; ++i)
#pragma unroll
          for (int n = 0; n < 4; ++n) acc[n] = MFMA(ao[i], bw[n * 8 + i], acc[n]);
        // check prefetched partner h(t-1); retry with fresh bypass loads
        const unsigned int tg = (unsigned int)t;
        unsigned long long q0 = pq0, q1 = pq1;
        for (;;) {
          if (__all(tag2ok(q0, tg) & tag2ok(q1, tg))) break;
          __builtin_amdgcn_s_sleep(1);
          q0 = ld64(sb); q1 = ld64(sb + 2);
        }
        const unsigned int lo = (unsigned)(q0 & 0xFFFF) | (((unsigned)(q0 >> 32) & 0xFFFF) << 16);
        const unsigned int hi = (unsigned)(q1 & 0xFFFF) | (((unsigned)(q1 >> 32) & 0xFFFF) << 16);
        *(uint2*)(Ab + ((srow * 512 + (po * 128 + spc) * 2) ^ ((srow & 7) << 4))) = (uint2){lo, hi};
      }
      wg_bar();   // partner staged
      if (t > 0) {
        s16x8 ap[4];
#pragma unroll
        for (int i = 0; i < 4; ++i) {
          const int ks = po * 4 + i;
          ap[i] = *(const s16x8*)(Ab + ((arow * 512 + (ks * 32 + kgrp * 8) * 2) ^ ((arow & 7) << 4)));
        }
#pragma unroll
        for (int i = 0; i < 4; ++i)
#pragma unroll
          for (int n = 0; n < 4; ++n) acc[n] = MFMA(ap[i], bw[n * 8 + 4 + i], acc[n]);
      }
      // EW per-lane; publish tagged (partner) + packed (L1) + LDS own-half
      const unsigned int tagw = (unsigned)(t + 1) << 16;
#pragma unroll
      for (int r = 0; r < 4; ++r) {
        const int row = kgrp * 4 + r;
        const float gi = acc[0][r] + bE[0] + xr[r] * xE[0];
        const float gf = acc[1][r] + bE[1] + xr[r] * xE[1];
        const float gg = acc[2][r] + bE[2] + xr[r] * xE[2];
        const float go = acc[3][r] + bE[3] + xr[r] * xE[3];
        cL[r] = sigm(gf) * cL[r] + sigm(gi) * tanh_f(gg);
        const float hv = sigm(go) * tanh_f(cL[r]);
        const unsigned short hb = f2bf(hv);
        st32(sr + (t & (D0 - 1)) * 4096 + row * 256 + U, tagw | hb);
        *(unsigned short*)(Ab + ((row * 512 + U * 2) ^ ((row & 7) << 4))) = hb;
        // packed publish for L1 (pair adjacent units via lane^1 shuffle)
        const float ov = __shfl_xor(hv, 1);
        if ((u16 & 1) == 0) {
          const unsigned int pk = (unsigned)hb | ((unsigned)f2bf(ov) << 16);
          st32(seq0p + ((size_t)t * BB + g * 16 + row) * 128 + (U >> 1), pk);
        }
      }
      drain_bar();   // all waves' seq0p/ring stores acked + EW LDS visible
      if (tid == 0) st32i(myflag, t + 1);
      // prefetch partner h(t) (validity tag-checked next step)
      {
        const unsigned int* pb = sr + (t & (D0 - 1)) * 4096 + srow * 256 + po * 128 + spc;
        pq0 = ld64(pb); pq1 = ld64(pb + 2);
      }
    }
  } else {
    // ========== LAYER 1: 4 WGs/group x 64 units, K=512 (Wx1|Wh1) ==========
    const int idx = bid - 8, g = idx >> 2, q = idx & 3;
    const int gp = w >> 2;            // gate pair
    const int uo = (w & 3) * 16;      // unit offset in WG's 64
    const int ub = q * 64;
    s16x8 bw[2][16];                  // static idx only
#pragma unroll
    for (int nt = 0; nt < 2; ++nt)
#pragma unroll
      for (int ks = 0; ks < 16; ++ks) {
        const int col = (2 * gp + nt) * 256 + ub + uo + u16;
#pragma unroll
        for (int j = 0; j < 8; ++j) {
          const int k = (ks & 7) * 32 + kgrp * 8 + j;
          bw[nt][ks][j] = (short)f2bf((ks < 8) ? Wx1[(size_t)k * 1024 + col]
                                               : Wh1[(size_t)k * 1024 + col]);
        }
      }
    const int eur = tid >> 5, eu2 = (tid & 31) * 2;
    float bE[4][2];
#pragma unroll
    for (int ga = 0; ga < 4; ++ga)
#pragma unroll
      for (int uu = 0; uu < 2; ++uu)
        bE[ga][uu] = b1v[ga * 256 + ub + eu2 + uu];

    unsigned int* hr = h1ring + (size_t)g * D1 * 4096;
    int* fA = &f0[(g * 2 + 0) * 16];
    int* fB = &f0[(g * 2 + 1) * 16];
    const int srow = tid >> 5;
    const int sc8  = (tid & 31) * 8;   // h1 tagged stage: 8 u32/thread
    const int k4   = (tid & 31) * 4;   // h0 packed: 4 u32 (uint4)/thread
    float cL[2] = {0.f, 0.f}, hs[2] = {0.f, 0.f};
    unsigned long long qh1[4];
    uint4 pf_h0;
    bool pf = false;

    if (tid == 0) smem_seen = 0;
    __syncthreads();

    for (int t = 0; t < TT; ++t) {
      // ---- h0(t): prefetched-cached or flag-gated cached load ----
      uint4 h0v;
      if (pf) {
        h0v = pf_h0;
      } else {
        if (tid == 0) {
          int s = smem_seen;
          if (s < t + 1) {
            do { int a = ld32i(fA), b = ld32i(fB); s = a < b ? a : b;
                 if (s < t + 1) __builtin_amdgcn_s_sleep(2); } while (s < t + 1);
          }
          smem_seen = s;
        }
        wg_bar();   // flag confirmed before loads
        h0v = *(const uint4*)(seq0p + ((size_t)t * BB + g * 16 + srow) * 128 + k4);
      }
      *(uint4*)(Ab + ((srow * 512 + k4 * 4) ^ ((srow & 7) << 4))) = h0v;
      // lazy non-blocking seen refresh (thread0; overlapped by others at bar)
      if (tid == 0) {
        int s0 = smem_seen;
        if (s0 < t + 3) {
          int a = ld32i(fA), b = ld32i(fB);
          int s = a < b ? a : b;
          if (s > s0) smem_seen = s;
        }
      }
      wg_bar();   // h0 staged
      f32x4 acc0 = {0,0,0,0}, acc1 = {0,0,0,0};
      {
        s16x8 a[8];
#pragma unroll
        for (int ks = 0; ks < 8; ++ks)
          a[ks] = *(const s16x8*)(Ab + ((arow * 512 + (ks * 32 + kgrp * 8) * 2) ^ ((arow & 7) << 4)));
#pragma unroll
        for (int ks = 0; ks < 8; ++ks) {
          acc0 = MFMA(a[ks], bw[0][ks], acc0);
          acc1 = MFMA(a[ks], bw[1][ks], acc1);
        }
      }
      // ---- h1(t-1): r10 tagged check (the one irreducible hop) ----
      if (t > 0) {
        const unsigned int* sbh1 = hr + ((t - 1) & (D1 - 1)) * 4096 + srow * 256 + sc8;
        const unsigned int tg = (unsigned int)t;
        for (;;) {
          bool ok = true;
#pragma unroll
          for (int i = 0; i < 4; ++i) ok &= tag2ok(qh1[i], tg);
          if (__all(ok)) break;
          __builtin_amdgcn_s_sleep(1);
#pragma unroll
          for (int i = 0; i < 4; ++i) qh1[i] = ld64(sbh1 + i * 2);
        }
        unsigned int wv[4];
#pragma unroll
        for (int i = 0; i < 4; ++i)
          wv[i] = (unsigned)(qh1[i] & 0xFFFF) | (((unsigned)(qh1[i] >> 32) & 0xFFFF) << 16);
        *(uint4*)(Ab1 + ((srow * 512 + sc8 * 2) ^ ((srow & 7) << 4))) =
            (uint4){wv[0], wv[1], wv[2], wv[3]};
      }
      wg_bar();   // h1 staged
      if (t > 0) {
        s16x8 a[8];
#pragma unroll
        for (int kk = 0; kk < 8; ++kk)
          a[kk] = *(const s16x8*)(Ab1 + ((arow * 512 + (kk * 32 + kgrp * 8) * 2) ^ ((arow & 7) << 4)));
#pragma unroll
        for (int kk = 0; kk < 8; ++kk) {
          acc0 = MFMA(a[kk], bw[0][8 + kk], acc0);
          acc1 = MFMA(a[kk], bw[1][8 + kk], acc1);
        }
      }
#pragma unroll
      for (int r = 0; r < 4; ++r) {
        gbuf[kgrp * 4 + r][2 * gp + 0][uo + u16] = acc0[r];
        gbuf[kgrp * 4 + r][2 * gp + 1][uo + u16] = acc1[r];
      }
      wg_bar();   // gates gathered (also orders smem_seen write)

      unsigned short hb[2];
#pragma unroll
      for (int uu = 0; uu < 2; ++uu) {
        const int u = eu2 + uu;
        const float gi = gbuf[eur][0][u] + bE[0][uu];
        const float gf = gbuf[eur][1][u] + bE[1][uu];
        const float gg = gbuf[eur][2][u] + bE[2][uu];
        const float go = gbuf[eur][3][u] + bE[3][uu];
        cL[uu] = sigm(gf) * cL[uu] + sigm(gi) * tanh_f(gg);
        const float hv = sigm(go) * tanh_f(cL[uu]);
        hs[uu] += hv;
        hb[uu] = f2bf(hv);
      }
      const unsigned int tagw = (unsigned)(t + 1) << 16;
      st32(hr + (t & (D1 - 1)) * 4096 + eur * 256 + ub + eu2,     tagw | hb[0]);
      st32(hr + (t & (D1 - 1)) * 4096 + eur * 256 + ub + eu2 + 1, tagw | hb[1]);
      // ---- prefetches for t+1 ----
      const int sE = smem_seen;                       // ordered by gates bar
      pf = (sE >= t + 2) && (t + 1 < TT);             // published BEFORE issue => valid
      if (pf)
        pf_h0 = *(const uint4*)(seq0p + ((size_t)(t + 1) * BB + g * 16 + srow) * 128 + k4);
      {
        const unsigned int* hb2 = hr + (t & (D1 - 1)) * 4096 + srow * 256 + sc8;
#pragma unroll
        for (int i = 0; i < 4; ++i) qh1[i] = ld64(hb2 + i * 2);
      }
    }
#pragma unroll
    for (int uu = 0; uu < 2; ++uu)
      hmean[(size_t)(g * 16 + eur) * HH + ub + eu2 + uu] = hs[uu] * (1.f / TT);
  }
}

__global__ __launch_bounds__(256)
void mlp_kernel(const float* __restrict__ theta, const float* __restrict__ Wtp,
                const float* __restrict__ btp, const float* __restrict__ Wl1,
                const float* __restrict__ bl1, const float* __restrict__ Wl2,
                const float* __restrict__ bl2, const float* __restrict__ Wo,
                const float* __restrict__ bo, const float* __restrict__ hmean,
                float* __restrict__ out)
{
  const int b = blockIdx.x;
  const int j = threadIdx.x;
  __shared__ float z[2 * HH];
  __shared__ float z1s[HH];
  __shared__ float red[256];

  float tp = btp[j];
#pragma unroll
  for (int d = 0; d < 5; ++d) tp += theta[b * 5 + d] * Wtp[d * HH + j];
  z[j] = hmean[(size_t)b * HH + j];
  z[HH + j] = tp;
  __syncthreads();

  float a1 = bl1[j];
  for (int k = 0; k < 2 * HH; ++k) a1 += z[k] * Wl1[(size_t)k * 256 + j];
  a1 = (a1 > 0.f) ? a1 : (__expf(a1) - 1.f);
  z1s[j] = a1;
  __syncthreads();

  float a2 = bl2[j];
  for (int k = 0; k < HH; ++k) a2 += z1s[k] * Wl2[(size_t)k * 256 + j];
  a2 = (a2 > 0.f) ? a2 : (__expf(a2) - 1.f);
  red[j] = a2 * Wo[j];
  __syncthreads();
  for (int s = 128; s > 0; s >>= 1) {
    if (j < s) red[j] += red[j + s];
    __syncthreads();
  }
  if (j == 0) out[b] = red[0] + bo[0];
}

extern "C" void kernel_launch(void* const* d_in, const int* in_sizes, int n_in,
                              void* d_out, int out_size, void* d_ws, size_t ws_size,
                              hipStream_t stream) {
  const float* x    = (const float*)d_in[0];
  const float* theta= (const float*)d_in[1];
  const float* Wx0  = (const float*)d_in[2];
  const float* Wh0  = (const float*)d_in[3];
  const float* b0   = (const float*)d_in[4];
  const float* Wx1  = (const float*)d_in[5];
  const float* Wh1  = (const float*)d_in[6];
  const float* b1   = (const float*)d_in[7];
  const float* Wtp  = (const float*)d_in[8];
  const float* btp  = (const float*)d_in[9];
  const float* Wl1  = (const float*)d_in[10];
  const float* bl1  = (const float*)d_in[11];
  const float* Wl2  = (const float*)d_in[12];
  const float* bl2  = (const float*)d_in[13];
  const float* Wo   = (const float*)d_in[14];
  const float* bo   = (const float*)d_in[15];

  // ws: flags 8KB | seqring [4][4][16][256] u32 256KB | h1ring [4][2][16][256] u32 128KB
  //     | hmean 64KB | seq0p packed [T][64][128] u32 64MB (append-only, no init)
  char* ws = (char*)d_ws;
  int* flags            = (int*)ws;
  unsigned int* seqring = (unsigned int*)(ws + 8192);
  unsigned int* h1ring  = (unsigned int*)(ws + 8192 + 262144);
  float* hmean          = (float*)(ws + 8192 + 262144 + 131072);
  unsigned int* seq0p   = (unsigned int*)(ws + 8192 + 262144 + 131072 + 65536);
  const size_t WS_NEED = 8192ull + 262144 + 131072 + 65536 +
                         (size_t)TT * BB * 128 * 4ull;
  if (ws_size < WS_NEED) return;   // fail visibly (d_out stays poisoned)

  hipMemsetAsync(d_ws, 0, 8192 + 262144 + 131072, stream);   // flags + rings

  lstm_kernel<<<dim3(24), dim3(512), 0, stream>>>(
      Wx0, Wh0, b0, Wx1, Wh1, b1, x, seqring, h1ring, seq0p, hmean, flags);
  mlp_kernel<<<dim3(BB), dim3(256), 0, stream>>>(
      theta, Wtp, btp, Wl1, bl1, Wl2, bl2, Wo, bo, hmean, (float*)d_out);
}

// Round 17
// 6262.016 us; speedup vs baseline: 5.7490x; 1.0025x over previous
//
#include <hip/hip_runtime.h>
#include <hip/hip_bf16.h>

// LSTMModel_with_theta: B=64, T=2048, H=256, 2-layer LSTM -> mean_t -> MLP.
//
// Round 17: r16 with ONE change: exchange loads issued at TOP of step.
//  - Ledger: r4 (3 hops) 3.3us/step vs r10/r16 (1 hop) 3.0us/step => per-hop
//    ~1.1us as implemented, but fabric says ~0.5us. Gap = guaranteed-stale
//    first check: end-of-step prefetch samples at peers' publish instant
//    (r15 insight) -> every step pays detect + full reload RTT.
//  - Fix: issue ONE fresh tagged load at top of step t (peers published
//    ~one barrier ago); own-MFMA section (~0.3us) covers the flight; memory-
//    side sample at +0.3us >= visibility (+0.2us) -> first check passes.
//    Applied to L0 partner check AND L1 h1 check. This is r11's timing
//    WITHOUT r11's confounds (coalesced gbuf EW publish kept, r12 lesson).
//  - Everything else r16 verbatim: h0 via packed seq0p + flags + pf-prefetch,
//    tagged u32 protocol, lgkmcnt-only bars, drain_bar on L0 publish.

#define BB 64
#define TT 2048
#define HH 256
#define D0 4
#define D1 2

typedef short s16x8 __attribute__((ext_vector_type(8)));
typedef float f32x4 __attribute__((ext_vector_type(4)));

__device__ inline unsigned short f2bf(float f) {
  unsigned u = __float_as_uint(f);
  u += 0x7fff + ((u >> 16) & 1);          // RNE
  return (unsigned short)(u >> 16);
}
__device__ inline float sigm(float x) { return 1.f / (1.f + __expf(-x)); }
__device__ inline float tanh_f(float x) { return 1.f - 2.f / (__expf(2.f * x) + 1.f); }

__device__ inline unsigned long long ld64(const unsigned int* p) {
  return __hip_atomic_load((const unsigned long long*)p, __ATOMIC_RELAXED,
                           __HIP_MEMORY_SCOPE_AGENT);
}
__device__ inline void st32(unsigned int* p, unsigned int v) {
  __hip_atomic_store(p, v, __ATOMIC_RELAXED, __HIP_MEMORY_SCOPE_AGENT);
}
__device__ inline void st32i(int* p, int v) {
  __hip_atomic_store(p, v, __ATOMIC_RELAXED, __HIP_MEMORY_SCOPE_AGENT);
}
__device__ inline int ld32i(const int* p) {
  return __hip_atomic_load(p, __ATOMIC_RELAXED, __HIP_MEMORY_SCOPE_AGENT);
}
// barrier, LDS-fence only (tagged global stores fly free)
__device__ inline void wg_bar() {
  asm volatile("s_waitcnt lgkmcnt(0)" ::: "memory");
  __builtin_amdgcn_sched_barrier(0);
  __builtin_amdgcn_s_barrier();
  __builtin_amdgcn_sched_barrier(0);
}
// producer-side full drain (global stores acked at coherence point + LDS)
__device__ inline void drain_bar() {
  asm volatile("s_waitcnt vmcnt(0) lgkmcnt(0)" ::: "memory");
  __builtin_amdgcn_sched_barrier(0);
  __builtin_amdgcn_s_barrier();
  __builtin_amdgcn_sched_barrier(0);
}
__device__ inline bool tag2ok(unsigned long long q, unsigned int tg) {
  return (((q >> 16) & 0xFFFFu) == tg) & ((unsigned)(q >> 48) == tg);
}

#define MFMA(a, b, c) __builtin_amdgcn_mfma_f32_16x16x32_bf16((a), (b), (c), 0, 0, 0)

__global__ __launch_bounds__(512, 1)
void lstm_kernel(const float* __restrict__ Wx0, const float* __restrict__ Wh0,
                 const float* __restrict__ b0v,
                 const float* __restrict__ Wx1, const float* __restrict__ Wh1,
                 const float* __restrict__ b1v,
                 const float* __restrict__ x,
                 unsigned int* __restrict__ seqring,   // [4][D0][16][256] tagged u32 (L0<->L0)
                 unsigned int* __restrict__ h1ring,    // [4][D1][16][256] tagged u32 (L1 peers)
                 unsigned int* __restrict__ seq0p,     // [T][64][128] packed bf16-pair u32
                 float* __restrict__ hmean, int* flags)
{
  __shared__ __align__(16) char Ab [8192];       // [16 rows][256 units] bf16, swizzled
  __shared__ __align__(16) char Ab1[8192];       // L1: h1(t-1)
  __shared__ float gbuf[16][4][66];              // L1 gate gather
  __shared__ int smem_seen;

  const int bid  = blockIdx.x;
  const int tid  = threadIdx.x;
  const int lane = tid & 63;
  const int w    = tid >> 6;      // wave 0..7
  const int u16  = lane & 15;
  const int kgrp = lane >> 4;
  const int arow = lane & 15;

  int* f0 = flags + 512;          // L0 publish flags: [(g*2+ho)*16]

  if (bid < 8) {
    // ========== LAYER 0: 2 WGs/group x 128 units, K=256 ==========
    const int g = bid >> 1, ho = bid & 1, po = 1 - ho;
    const int U = ho * 128 + w * 16 + u16;       // lane's unit (all 4 gates)
    s16x8 bw[32];                                // phase layout, static reg indices
#pragma unroll
    for (int n = 0; n < 4; ++n)
#pragma unroll
      for (int ph = 0; ph < 2; ++ph)
#pragma unroll
        for (int i = 0; i < 4; ++i) {
          const int ks = (ph == 0 ? ho : po) * 4 + i;   // runtime, address-only
          const int col = n * 256 + U;
#pragma unroll
          for (int j = 0; j < 8; ++j)
            bw[n * 8 + ph * 4 + i][j] =
                (short)f2bf(Wh0[(size_t)(ks * 32 + kgrp * 8 + j) * 1024 + col]);
        }
    float bE[4], xE[4];
#pragma unroll
    for (int n = 0; n < 4; ++n) { bE[n] = b0v[n * 256 + U]; xE[n] = Wx0[n * 256 + U]; }

    unsigned int* sr = seqring + (size_t)g * D0 * 4096;
    int* myflag = &f0[(g * 2 + ho) * 16];
    const int srow = tid >> 5, spc = (tid & 31) * 4;    // partner stage: 4 u32/thread
    float cL[4] = {0.f, 0.f, 0.f, 0.f};

    for (int t = 0; t < TT; ++t) {
      // x loads early (64B line covers 16 t's -> L1-hit most steps)
      float xr[4];
#pragma unroll
      for (int r = 0; r < 4; ++r) xr[r] = x[(size_t)(g * 16 + kgrp * 4 + r) * TT + t];

      // TOP-ISSUED partner load: peers published ~one barrier ago; own-MFMA
      // section below covers the flight -> first check passes steady-state.
      const unsigned int* sb = sr + ((t - 1) & (D0 - 1)) * 4096 + srow * 256 + po * 128 + spc;
      unsigned long long q0 = 0, q1 = 0;
      if (t > 0) { q0 = ld64(sb); q1 = ld64(sb + 2); }

      f32x4 acc[4] = {{0,0,0,0},{0,0,0,0},{0,0,0,0},{0,0,0,0}};
      if (t > 0) {
        // own-half MFMAs from LDS (cover the in-flight partner load)
        s16x8 ao[4];
#pragma unroll
        for (int i = 0; i < 4; ++i) {
          const int ks = ho * 4 + i;
          ao[i] = *(const s16x8*)(Ab + ((arow * 512 + (ks * 32 + kgrp * 8) * 2) ^ ((arow & 7) << 4)));
        }
#pragma unroll
        for (int i = 0; i < 4; ++i)
#pragma unroll
          for (int n = 0; n < 4; ++n) acc[n] = MFMA(ao[i], bw[n * 8 + i], acc[n]);
        // check top-issued load; retry with fresh bypass loads on miss
        const unsigned int tg = (unsigned int)t;
        for (;;) {
          if (__all(tag2ok(q0, tg) & tag2ok(q1, tg))) break;
          __builtin_amdgcn_s_sleep(1);
          q0 = ld64(sb); q1 = ld64(sb + 2);
        }
        const unsigned int lo = (unsigned)(q0 & 0xFFFF) | (((unsigned)(q0 >> 32) & 0xFFFF) << 16);
        const unsigned int hi = (unsigned)(q1 & 0xFFFF) | (((unsigned)(q1 >> 32) & 0xFFFF) << 16);
        *(uint2*)(Ab + ((srow * 512 + (po * 128 + spc) * 2) ^ ((srow & 7) << 4))) = (uint2){lo, hi};
      }
      wg_bar();   // partner staged
      if (t > 0) {
        s16x8 ap[4];
#pragma unroll
        for (int i = 0; i < 4; ++i) {
          const int ks = po * 4 + i;
          ap[i] = *(const s16x8*)(Ab + ((arow * 512 + (ks * 32 + kgrp * 8) * 2) ^ ((arow & 7) << 4)));
        }
#pragma unroll
        for (int i = 0; i < 4; ++i)
#pragma unroll
          for (int n = 0; n < 4; ++n) acc[n] = MFMA(ap[i], bw[n * 8 + 4 + i], acc[n]);
      }
      // EW per-lane; publish tagged (partner) + packed (L1) + LDS own-half
      const unsigned int tagw = (unsigned)(t + 1) << 16;
#pragma unroll
      for (int r = 0; r < 4; ++r) {
        const int row = kgrp * 4 + r;
        const float gi = acc[0][r] + bE[0] + xr[r] * xE[0];
        const float gf = acc[1][r] + bE[1] + xr[r] * xE[1];
        const float gg = acc[2][r] + bE[2] + xr[r] * xE[2];
        const float go = acc[3][r] + bE[3] + xr[r] * xE[3];
        cL[r] = sigm(gf) * cL[r] + sigm(gi) * tanh_f(gg);
        const float hv = sigm(go) * tanh_f(cL[r]);
        const unsigned short hb = f2bf(hv);
        st32(sr + (t & (D0 - 1)) * 4096 + row * 256 + U, tagw | hb);
        *(unsigned short*)(Ab + ((row * 512 + U * 2) ^ ((row & 7) << 4))) = hb;
        // packed publish for L1 (pair adjacent units via lane^1 shuffle)
        const float ov = __shfl_xor(hv, 1);
        if ((u16 & 1) == 0) {
          const unsigned int pk = (unsigned)hb | ((unsigned)f2bf(ov) << 16);
          st32(seq0p + ((size_t)t * BB + g * 16 + row) * 128 + (U >> 1), pk);
        }
      }
      drain_bar();   // all waves' seq0p/ring stores acked + EW LDS visible
      if (tid == 0) st32i(myflag, t + 1);
    }
  } else {
    // ========== LAYER 1: 4 WGs/group x 64 units, K=512 (Wx1|Wh1) ==========
    const int idx = bid - 8, g = idx >> 2, q = idx & 3;
    const int gp = w >> 2;            // gate pair
    const int uo = (w & 3) * 16;      // unit offset in WG's 64
    const int ub = q * 64;
    s16x8 bw[2][16];                  // static idx only
#pragma unroll
    for (int nt = 0; nt < 2; ++nt)
#pragma unroll
      for (int ks = 0; ks < 16; ++ks) {
        const int col = (2 * gp + nt) * 256 + ub + uo + u16;
#pragma unroll
        for (int j = 0; j < 8; ++j) {
          const int k = (ks & 7) * 32 + kgrp * 8 + j;
          bw[nt][ks][j] = (short)f2bf((ks < 8) ? Wx1[(size_t)k * 1024 + col]
                                               : Wh1[(size_t)k * 1024 + col]);
        }
      }
    const int eur = tid >> 5, eu2 = (tid & 31) * 2;
    float bE[4][2];
#pragma unroll
    for (int ga = 0; ga < 4; ++ga)
#pragma unroll
      for (int uu = 0; uu < 2; ++uu)
        bE[ga][uu] = b1v[ga * 256 + ub + eu2 + uu];

    unsigned int* hr = h1ring + (size_t)g * D1 * 4096;
    int* fA = &f0[(g * 2 + 0) * 16];
    int* fB = &f0[(g * 2 + 1) * 16];
    const int srow = tid >> 5;
    const int sc8  = (tid & 31) * 8;   // h1 tagged stage: 8 u32/thread
    const int k4   = (tid & 31) * 4;   // h0 packed: 4 u32 (uint4)/thread
    float cL[2] = {0.f, 0.f}, hs[2] = {0.f, 0.f};
    uint4 pf_h0;
    bool pf = false;

    if (tid == 0) smem_seen = 0;
    __syncthreads();

    for (int t = 0; t < TT; ++t) {
      // TOP-ISSUED h1(t-1) load: peers published at their step-(t-1) end;
      // the whole h0 phase below covers the flight.
      const unsigned int* sbh1 = hr + ((t - 1) & (D1 - 1)) * 4096 + srow * 256 + sc8;
      unsigned long long qh1[4];
      if (t > 0) {
#pragma unroll
        for (int i = 0; i < 4; ++i) qh1[i] = ld64(sbh1 + i * 2);
      }
      // ---- h0(t): prefetched-cached or flag-gated cached load ----
      uint4 h0v;
      if (pf) {
        h0v = pf_h0;
      } else {
        if (tid == 0) {
          int s = smem_seen;
          if (s < t + 1) {
            do { int a = ld32i(fA), b = ld32i(fB); s = a < b ? a : b;
                 if (s < t + 1) __builtin_amdgcn_s_sleep(2); } while (s < t + 1);
          }
          smem_seen = s;
        }
        wg_bar();   // flag confirmed before loads
        h0v = *(const uint4*)(seq0p + ((size_t)t * BB + g * 16 + srow) * 128 + k4);
      }
      *(uint4*)(Ab + ((srow * 512 + k4 * 4) ^ ((srow & 7) << 4))) = h0v;
      // lazy non-blocking seen refresh (thread0; overlapped by others at bar)
      if (tid == 0) {
        int s0 = smem_seen;
        if (s0 < t + 3) {
          int a = ld32i(fA), b = ld32i(fB);
          int s = a < b ? a : b;
          if (s > s0) smem_seen = s;
        }
      }
      wg_bar();   // h0 staged
      f32x4 acc0 = {0,0,0,0}, acc1 = {0,0,0,0};
      {
        s16x8 a[8];
#pragma unroll
        for (int ks = 0; ks < 8; ++ks)
          a[ks] = *(const s16x8*)(Ab + ((arow * 512 + (ks * 32 + kgrp * 8) * 2) ^ ((arow & 7) << 4)));
#pragma unroll
        for (int ks = 0; ks < 8; ++ks) {
          acc0 = MFMA(a[ks], bw[0][ks], acc0);
          acc1 = MFMA(a[ks], bw[1][ks], acc1);
        }
      }
      // ---- h1(t-1): check top-issued load (the one irreducible hop) ----
      if (t > 0) {
        const unsigned int tg = (unsigned int)t;
        for (;;) {
          bool ok = true;
#pragma unroll
          for (int i = 0; i < 4; ++i) ok &= tag2ok(qh1[i], tg);
          if (__all(ok)) break;
          __builtin_amdgcn_s_sleep(1);
#pragma unroll
          for (int i = 0; i < 4; ++i) qh1[i] = ld64(sbh1 + i * 2);
        }
        unsigned int wv[4];
#pragma unroll
        for (int i = 0; i < 4; ++i)
          wv[i] = (unsigned)(qh1[i] & 0xFFFF) | (((unsigned)(qh1[i] >> 32) & 0xFFFF) << 16);
        *(uint4*)(Ab1 + ((srow * 512 + sc8 * 2) ^ ((srow & 7) << 4))) =
            (uint4){wv[0], wv[1], wv[2], wv[3]};
      }
      wg_bar();   // h1 staged
      if (t > 0) {
        s16x8 a[8];
#pragma unroll
        for (int kk = 0; kk < 8; ++kk)
          a[kk] = *(const s16x8*)(Ab1 + ((arow * 512 + (kk * 32 + kgrp * 8) * 2) ^ ((arow & 7) << 4)));
#pragma unroll
        for (int kk = 0; kk < 8; ++kk) {
          acc0 = MFMA(a[kk], bw[0][8 + kk], acc0);
          acc1 = MFMA(a[kk], bw[1][8 + kk], acc1);
        }
      }
#pragma unroll
      for (int r = 0; r < 4; ++r) {
        gbuf[kgrp * 4 + r][2 * gp + 0][uo + u16] = acc0[r];
        gbuf[kgrp * 4 + r][2 * gp + 1][uo + u16] = acc1[r];
      }
      wg_bar();   // gates gathered (also orders smem_seen write)

      unsigned short hb[2];
#pragma unroll
      for (int uu = 0; uu < 2; ++uu) {
        const int u = eu2 + uu;
        const float gi = gbuf[eur][0][u] + bE[0][uu];
        const float gf = gbuf[eur][1][u] + bE[1][uu];
        const float gg = gbuf[eur][2][u] + bE[2][uu];
        const float go = gbuf[eur][3][u] + bE[3][uu];
        cL[uu] = sigm(gf) * cL[uu] + sigm(gi) * tanh_f(gg);
        const float hv = sigm(go) * tanh_f(cL[uu]);
        hs[uu] += hv;
        hb[uu] = f2bf(hv);
      }
      const unsigned int tagw = (unsigned)(t + 1) << 16;
      st32(hr + (t & (D1 - 1)) * 4096 + eur * 256 + ub + eu2,     tagw | hb[0]);
      st32(hr + (t & (D1 - 1)) * 4096 + eur * 256 + ub + eu2 + 1, tagw | hb[1]);
      // ---- h0 prefetch for t+1 (valid: published BEFORE issue) ----
      const int sE = smem_seen;                       // ordered by gates bar
      pf = (sE >= t + 2) && (t + 1 < TT);
      if (pf)
        pf_h0 = *(const uint4*)(seq0p + ((size_t)(t + 1) * BB + g * 16 + srow) * 128 + k4);
    }
#pragma unroll
    for (int uu = 0; uu < 2; ++uu)
      hmean[(size_t)(g * 16 + eur) * HH + ub + eu2 + uu] = hs[uu] * (1.f / TT);
  }
}

__global__ __launch_bounds__(256)
void mlp_kernel(const float* __restrict__ theta, const float* __restrict__ Wtp,
                const float* __restrict__ btp, const float* __restrict__ Wl1,
                const float* __restrict__ bl1, const float* __restrict__ Wl2,
                const float* __restrict__ bl2, const float* __restrict__ Wo,
                const float* __restrict__ bo, const float* __restrict__ hmean,
                float* __restrict__ out)
{
  const int b = blockIdx.x;
  const int j = threadIdx.x;
  __shared__ float z[2 * HH];
  __shared__ float z1s[HH];
  __shared__ float red[256];

  float tp = btp[j];
#pragma unroll
  for (int d = 0; d < 5; ++d) tp += theta[b * 5 + d] * Wtp[d * HH + j];
  z[j] = hmean[(size_t)b * HH + j];
  z[HH + j] = tp;
  __syncthreads();

  float a1 = bl1[j];
  for (int k = 0; k < 2 * HH; ++k) a1 += z[k] * Wl1[(size_t)k * 256 + j];
  a1 = (a1 > 0.f) ? a1 : (__expf(a1) - 1.f);
  z1s[j] = a1;
  __syncthreads();

  float a2 = bl2[j];
  for (int k = 0; k < HH; ++k) a2 += z1s[k] * Wl2[(size_t)k * 256 + j];
  a2 = (a2 > 0.f) ? a2 : (__expf(a2) - 1.f);
  red[j] = a2 * Wo[j];
  __syncthreads();
  for (int s = 128; s > 0; s >>= 1) {
    if (j < s) red[j] += red[j + s];
    __syncthreads();
  }
  if (j == 0) out[b] = red[0] + bo[0];
}

extern "C" void kernel_launch(void* const* d_in, const int* in_sizes, int n_in,
                              void* d_out, int out_size, void* d_ws, size_t ws_size,
                              hipStream_t stream) {
  const float* x    = (const float*)d_in[0];
  const float* theta= (const float*)d_in[1];
  const float* Wx0  = (const float*)d_in[2];
  const float* Wh0  = (const float*)d_in[3];
  const float* b0   = (const float*)d_in[4];
  const float* Wx1  = (const float*)d_in[5];
  const float* Wh1  = (const float*)d_in[6];
  const float* b1   = (const float*)d_in[7];
  const float* Wtp  = (const float*)d_in[8];
  const float* btp  = (const float*)d_in[9];
  const float* Wl1  = (const float*)d_in[10];
  const float* bl1  = (const float*)d_in[11];
  const float* Wl2  = (const float*)d_in[12];
  const float* bl2  = (const float*)d_in[13];
  const float* Wo   = (const float*)d_in[14];
  const float* bo   = (const float*)d_in[15];

  // ws: flags 8KB | seqring [4][4][16][256] u32 256KB | h1ring [4][2][16][256] u32 128KB
  //     | hmean 64KB | seq0p packed [T][64][128] u32 64MB (append-only, no init)
  char* ws = (char*)d_ws;
  int* flags            = (int*)ws;
  unsigned int* seqring = (unsigned int*)(ws + 8192);
  unsigned int* h1ring  = (unsigned int*)(ws + 8192 + 262144);
  float* hmean          = (float*)(ws + 8192 + 262144 + 131072);
  unsigned int* seq0p   = (unsigned int*)(ws + 8192 + 262144 + 131072 + 65536);
  const size_t WS_NEED = 8192ull + 262144 + 131072 + 65536 +
                         (size_t)TT * BB * 128 * 4ull;
  if (ws_size < WS_NEED) return;   // fail visibly (d_out stays poisoned)

  hipMemsetAsync(d_ws, 0, 8192 + 262144 + 131072, stream);   // flags + rings

  lstm_kernel<<<dim3(24), dim3(512), 0, stream>>>(
      Wx0, Wh0, b0, Wx1, Wh1, b1, x, seqring, h1ring, seq0p, hmean, flags);
  mlp_kernel<<<dim3(BB), dim3(256), 0, stream>>>(
      theta, Wtp, btp, Wl1, bl1, Wl2, bl2, Wo, bo, hmean, (float*)d_out);
}